// Round 3
// baseline (32273.578 us; speedup 1.0000x reference)
//
#include <hip/hip_runtime.h>

typedef unsigned short u16;
typedef unsigned int u32;

using bf16x8 = __attribute__((ext_vector_type(8))) __bf16;
using f32x4  = __attribute__((ext_vector_type(4))) float;

#define T_DIM 512
#define B_DIM 256
#define E_DIM 512
#define U_DIM 1024
#define K_DIM 1536   /* E+U */
#define NG    2048   /* 2U */
#define NWG   128    /* persistent grid: 1 WG/CU by LDS, 2x CU slack */

__device__ __forceinline__ u16 f2bf(float f) {
  union { float f; u32 u; } v; v.f = f;
  return (u16)((v.u + 0x7fffu + ((v.u >> 16) & 1u)) >> 16);
}

__global__ __launch_bounds__(256) void init_kernel(float* hF, u16* hB, int* bar) {
  int i = blockIdx.x * 256 + threadIdx.x;
  hF[i] = 0.f;
  hB[i] = 0;
  if (i < 2) bar[i] = 0;
}

// W [K_DIM][N] fp32 -> Wt [N][K_DIM] bf16
__global__ __launch_bounds__(256) void wconv_kernel(const float* __restrict__ W,
                                                    u16* __restrict__ Wt, int N) {
  int k = blockIdx.x * 64 + (threadIdx.x & 63);
  int n = blockIdx.y * 4 + (threadIdx.x >> 6);
  Wt[(size_t)n * K_DIM + k] = f2bf(W[(size_t)k * N + n]);
}

// X[t*B+b][e] = bf16(embedder[inputs[t*B+b]][e])
__global__ __launch_bounds__(128) void embed_kernel(const int* __restrict__ inp,
                                                    const float* __restrict__ emb,
                                                    u16* __restrict__ X) {
  int rb = blockIdx.x;
  int idx = inp[rb];
  int e = threadIdx.x * 4;
  float4 v = *(const float4*)&emb[(size_t)idx * E_DIM + e];
  ushort4 o;
  o.x = f2bf(v.x); o.y = f2bf(v.y); o.z = f2bf(v.z); o.w = f2bf(v.w);
  *(ushort4*)&X[(size_t)rb * E_DIM + e] = o;
}

// Swizzled LDS weight read: logical [48 cols][1536 k] bf16, row stride 3072 B.
__device__ __forceinline__ bf16x8 ldsW(const u16* Wl, int lc, int k) {
  int ofs = lc * 3072 + k * 2;
  ofs ^= ((lc & 7) << 4);
  return *(const bf16x8*)((const char*)Wl + ofs);
}

// Hand-rolled grid barrier (device-scope). bar[0]=count, bar[1]=generation.
__device__ __forceinline__ void grid_barrier(int* cnt, int* gen) {
  __syncthreads();  // all waves' stores drained to L2 (vmcnt(0) before s_barrier)
  if (threadIdx.x == 0) {
    __threadfence();  // L2 writeback: release my WG's data device-wide
    int g = __hip_atomic_load(gen, __ATOMIC_RELAXED, __HIP_MEMORY_SCOPE_AGENT);
    int prev = __hip_atomic_fetch_add(cnt, 1, __ATOMIC_ACQ_REL, __HIP_MEMORY_SCOPE_AGENT);
    if (prev == NWG - 1) {
      __hip_atomic_store(cnt, 0, __ATOMIC_RELAXED, __HIP_MEMORY_SCOPE_AGENT);
      __hip_atomic_fetch_add(gen, 1, __ATOMIC_RELEASE, __HIP_MEMORY_SCOPE_AGENT);
    } else {
      while (__hip_atomic_load(gen, __ATOMIC_RELAXED, __HIP_MEMORY_SCOPE_AGENT) == g) {
        __builtin_amdgcn_s_sleep(2);
      }
    }
    __threadfence();  // L2 invalidate: acquire remote WGs' data
  }
  __syncthreads();
}

// Persistent GRU loop, regular launch.
// Grid: 128 WGs x 256 thr. WG = (col-tile ct in [0,64)) x (row-half mh in [0,2)).
// ct owns gate cols [ct*32,+32) and cand cols [ct*16,+16); mh owns rows [mh*128,+128).
// Weights for the 48 cols (K=1536) live in LDS for the whole kernel (144 KB).
__global__ void __launch_bounds__(256, 1) gru_loop(
    const u16* __restrict__ X, const u16* __restrict__ WgT,
    const u16* __restrict__ WcT, const float* __restrict__ bg,
    const float* __restrict__ bc, float* __restrict__ hF,
    u16* __restrict__ hB, u16* __restrict__ rhB, float* __restrict__ zb,
    const int* __restrict__ lens, int* bar) {
  __shared__ __align__(16) u16 Wl[48 * K_DIM];  // 147456 B
  const int tid = threadIdx.x;
  const int ct = blockIdx.x >> 1;
  const int mh = blockIdx.x & 1;

  // Stage weights once: 48 cols x 1536 k = 9216 chunks of 8 bf16.
#pragma unroll 4
  for (int it = 0; it < 36; ++it) {
    int ci = it * 256 + tid;
    int lc = ci / 192;                 // 192 = 1536/8 chunks per col
    int k0 = (ci - lc * 192) * 8;
    const u16* src = (lc < 32)
        ? WgT + (size_t)(ct * 32 + lc) * K_DIM + k0
        : WcT + (size_t)(ct * 16 + (lc - 32)) * K_DIM + k0;
    uint4 v = *(const uint4*)src;
    int ofs = lc * 3072 + k0 * 2;
    ofs ^= ((lc & 7) << 4);
    *(uint4*)((char*)Wl + ofs) = v;
  }
  __syncthreads();

  const int lane = tid & 63, wv = tid >> 6;
  const int l15 = lane & 15;
  const int kq8 = (lane >> 4) * 8;
  const int lq4 = (lane >> 4) * 4;
  const int rbase = mh * 128 + wv * 32;  // this wave's 32 rows
  int* cnt = bar;
  int* gen = bar + 1;

  for (int t = 0; t < T_DIM; ++t) {
    // ---- Phase A: gates = sigmoid([x,h] @ Wg + bg) -> rh, z ----
#pragma unroll
    for (int mi = 0; mi < 2; ++mi) {
      const int arow = rbase + mi * 16 + l15;
      const u16* Xt = X + ((size_t)t * B_DIM + arow) * E_DIM + kq8;
      const u16* Hp = hB + (size_t)arow * U_DIM + kq8;
      bf16x8 af[48];
#pragma unroll
      for (int kb = 0; kb < 16; ++kb) af[kb] = *(const bf16x8*)(Xt + kb * 32);
#pragma unroll
      for (int kb = 0; kb < 32; ++kb) af[16 + kb] = *(const bf16x8*)(Hp + kb * 32);
      f32x4 a0 = {0.f, 0.f, 0.f, 0.f}, a1 = {0.f, 0.f, 0.f, 0.f};
#pragma unroll
      for (int kb = 0; kb < 48; ++kb) {
        bf16x8 b0 = ldsW(Wl, l15, kb * 32 + kq8);
        bf16x8 b1 = ldsW(Wl, 16 + l15, kb * 32 + kq8);
        a0 = __builtin_amdgcn_mfma_f32_16x16x32_bf16(af[kb], b0, a0, 0, 0, 0);
        a1 = __builtin_amdgcn_mfma_f32_16x16x32_bf16(af[kb], b1, a1, 0, 0, 0);
      }
#pragma unroll
      for (int j = 0; j < 2; ++j) {
        f32x4 acc = j ? a1 : a0;
        int n = ct * 32 + j * 16 + l15;
        float bias = bg[n];
#pragma unroll
        for (int q = 0; q < 4; ++q) {
          int row = rbase + mi * 16 + lq4 + q;
          float g = 1.f / (1.f + __expf(-(acc[q] + bias)));
          if (ct < 32) {  // r half: n < 1024
            size_t o = (size_t)row * U_DIM + n;
            rhB[o] = f2bf(g * hF[o]);
          } else {        // z half
            zb[(size_t)row * U_DIM + (n - U_DIM)] = g;
          }
        }
      }
    }
    grid_barrier(cnt, gen);

    // ---- Phase B: cand = tanh([x, rh] @ Wc + bc); h update ----
#pragma unroll
    for (int mi = 0; mi < 2; ++mi) {
      const int arow = rbase + mi * 16 + l15;
      const u16* Xt = X + ((size_t)t * B_DIM + arow) * E_DIM + kq8;
      const u16* Rp = rhB + (size_t)arow * U_DIM + kq8;
      bf16x8 af[48];
#pragma unroll
      for (int kb = 0; kb < 16; ++kb) af[kb] = *(const bf16x8*)(Xt + kb * 32);
#pragma unroll
      for (int kb = 0; kb < 32; ++kb) af[16 + kb] = *(const bf16x8*)(Rp + kb * 32);
      f32x4 a2 = {0.f, 0.f, 0.f, 0.f};
#pragma unroll
      for (int kb = 0; kb < 48; ++kb) {
        bf16x8 b2 = ldsW(Wl, 32 + l15, kb * 32 + kq8);
        a2 = __builtin_amdgcn_mfma_f32_16x16x32_bf16(af[kb], b2, a2, 0, 0, 0);
      }
      int nc = ct * 16 + l15;
      float bias = bc[nc];
#pragma unroll
      for (int q = 0; q < 4; ++q) {
        int row = rbase + mi * 16 + lq4 + q;
        float c = tanhf(a2[q] + bias);
        size_t o = (size_t)row * U_DIM + nc;
        float hold = hF[o];
        float z = zb[o];
        float hn = z * hold + (1.f - z) * c;
        float v = (t < lens[row]) ? hn : hold;
        hF[o] = v;
        hB[o] = f2bf(v);
      }
    }
    grid_barrier(cnt, gen);
  }
}

__global__ __launch_bounds__(256) void mlp1_kernel(const float* __restrict__ h,
                                                   const float* __restrict__ W1,
                                                   const float* __restrict__ b1,
                                                   float* __restrict__ o1) {
  int m = blockIdx.x, tid = threadIdx.x;
  __shared__ float xs[1024];
  for (int k = tid; k < 1024; k += 256) xs[k] = h[(size_t)m * 1024 + k];
  __syncthreads();
  for (int n = tid; n < 512; n += 256) {
    float s = b1[n];
    for (int k = 0; k < 1024; ++k) s += xs[k] * W1[(size_t)k * 512 + n];
    o1[(size_t)m * 512 + n] = fmaxf(s, 0.f);
  }
}

__global__ __launch_bounds__(256) void mlp2_kernel(const float* __restrict__ x,
                                                   const float* __restrict__ W2,
                                                   const float* __restrict__ b2,
                                                   float* __restrict__ o2) {
  int m = blockIdx.x, tid = threadIdx.x;
  __shared__ float xs[512];
  for (int k = tid; k < 512; k += 256) xs[k] = x[(size_t)m * 512 + k];
  __syncthreads();
  int n = tid;
  float s = b2[n];
  for (int k = 0; k < 512; ++k) s += xs[k] * W2[(size_t)k * 256 + n];
  o2[(size_t)m * 256 + n] = fmaxf(s, 0.f);
}

__global__ __launch_bounds__(256) void mlp3_kernel(const float* __restrict__ x,
                                                   const float* __restrict__ W3,
                                                   const float* __restrict__ b3,
                                                   float* __restrict__ out) {
  int m = blockIdx.x, tid = threadIdx.x;
  float xk = x[(size_t)m * 256 + tid];
  float p0 = xk * W3[tid * 2 + 0];
  float p1 = xk * W3[tid * 2 + 1];
#pragma unroll
  for (int off = 32; off; off >>= 1) {
    p0 += __shfl_down(p0, off);
    p1 += __shfl_down(p1, off);
  }
  __shared__ float s0[4], s1[4];
  int wave = tid >> 6, lane = tid & 63;
  if (lane == 0) { s0[wave] = p0; s1[wave] = p1; }
  __syncthreads();
  if (tid == 0) {
    float l0 = s0[0] + s0[1] + s0[2] + s0[3] + b3[0];
    float l1 = s1[0] + s1[1] + s1[2] + s1[3] + b3[1];
    out[m * 2 + 0] = l0;
    out[m * 2 + 1] = l1;
    float mx = fmaxf(l0, l1);
    float e0 = __expf(l0 - mx), e1 = __expf(l1 - mx);
    float inv = 1.f / (e0 + e1);
    out[512 + m * 2 + 0] = e0 * inv;
    out[512 + m * 2 + 1] = e1 * inv;
  }
}

extern "C" void kernel_launch(void* const* d_in, const int* in_sizes, int n_in,
                              void* d_out, int out_size, void* d_ws, size_t ws_size,
                              hipStream_t stream) {
  (void)in_sizes; (void)n_in; (void)out_size; (void)ws_size;
  const int* inputs = (const int*)d_in[0];
  const int* lens = (const int*)d_in[1];
  const float* embedder = (const float*)d_in[2];
  const float* Wg = (const float*)d_in[3];
  const float* bg = (const float*)d_in[4];
  const float* Wc = (const float*)d_in[5];
  const float* bc = (const float*)d_in[6];
  const float* W1 = (const float*)d_in[7];
  const float* b1 = (const float*)d_in[8];
  const float* W2 = (const float*)d_in[9];
  const float* b2 = (const float*)d_in[10];
  const float* W3 = (const float*)d_in[11];
  const float* b3 = (const float*)d_in[12];
  float* out = (float*)d_out;

  char* ws = (char*)d_ws;
  size_t off = 0;
  u16* X = (u16*)(ws + off);       off += (size_t)T_DIM * B_DIM * E_DIM * 2;   // 134.2 MB
  u16* WgT = (u16*)(ws + off);     off += (size_t)NG * K_DIM * 2;              // 6.3 MB
  u16* WcT = (u16*)(ws + off);     off += (size_t)U_DIM * K_DIM * 2;           // 3.1 MB
  float* hF = (float*)(ws + off);  off += (size_t)B_DIM * U_DIM * 4;
  u16* hB = (u16*)(ws + off);      off += (size_t)B_DIM * U_DIM * 2;
  u16* rhB = (u16*)(ws + off);     off += (size_t)B_DIM * U_DIM * 2;
  float* zb = (float*)(ws + off);  off += (size_t)B_DIM * U_DIM * 4;
  float* o1 = (float*)(ws + off);  off += (size_t)B_DIM * 512 * 4;
  float* o2 = (float*)(ws + off);  off += (size_t)B_DIM * 256 * 4;
  int* bar = (int*)(ws + off);     off += 256;

  init_kernel<<<dim3(1024), dim3(256), 0, stream>>>(hF, hB, bar);
  wconv_kernel<<<dim3(24, 512), dim3(256), 0, stream>>>(Wg, WgT, NG);
  wconv_kernel<<<dim3(24, 256), dim3(256), 0, stream>>>(Wc, WcT, U_DIM);
  embed_kernel<<<dim3(T_DIM * B_DIM), dim3(128), 0, stream>>>(inputs, embedder, X);

  gru_loop<<<dim3(NWG), dim3(256), 0, stream>>>(X, WgT, WcT, bg, bc, hF, hB, rhB,
                                                zb, lens, bar);

  mlp1_kernel<<<dim3(256), dim3(256), 0, stream>>>(hF, W1, b1, o1);
  mlp2_kernel<<<dim3(256), dim3(256), 0, stream>>>(o1, W2, b2, o2);
  mlp3_kernel<<<dim3(256), dim3(256), 0, stream>>>(o2, W3, b3, out);
}

// Round 4
// 17767.230 us; speedup vs baseline: 1.8165x; 1.8165x over previous
//
#include <hip/hip_runtime.h>

typedef unsigned short u16;
typedef unsigned int u32;
typedef unsigned long long u64;

using bf16x8 = __attribute__((ext_vector_type(8))) __bf16;
using f32x4  = __attribute__((ext_vector_type(4))) float;

#define T_DIM 512
#define B_DIM 256
#define E_DIM 512
#define U_DIM 1024
#define K_DIM 1536   /* E+U */
#define NG    2048   /* 2U */
#define NWG   256    /* persistent grid: 1 WG/CU on all 256 CUs */

__device__ __forceinline__ u16 f2bf(float f) {
  union { float f; u32 u; } v; v.f = f;
  return (u16)((v.u + 0x7fffu + ((v.u >> 16) & 1u)) >> 16);
}

// ---- device-coherent (cross-XCD) memory ops: sc0 sc1 bypasses the
// ---- non-coherent per-XCD L2 so no buffer_wbl2/inv fences are needed.
#define WAIT_VM_ALL() do { asm volatile("s_waitcnt vmcnt(0)" ::: "memory"); \
                           __builtin_amdgcn_sched_barrier(0); } while (0)

__device__ __forceinline__ void ld16_sc(bf16x8* d, const u16* p) {
  asm volatile("global_load_dwordx4 %0, %1, off sc0 sc1" : "=&v"(*d) : "v"(p));
}
__device__ __forceinline__ void ld4f_sc(float* d, const float* p) {
  asm volatile("global_load_dword %0, %1, off sc0 sc1" : "=&v"(*d) : "v"(p));
}
__device__ __forceinline__ void st4f_sc(float* p, float v) {
  asm volatile("global_store_dword %0, %1, off sc0 sc1" :: "v"(p), "v"(v) : "memory");
}
__device__ __forceinline__ void st2_sc(u16* p, u16 v) {
  asm volatile("global_store_short %0, %1, off sc0 sc1" :: "v"(p), "v"(v) : "memory");
}

__global__ __launch_bounds__(256) void init_kernel(float* hF, u16* hB, int* bar) {
  int i = blockIdx.x * 256 + threadIdx.x;
  hF[i] = 0.f;
  hB[i] = 0;
  if (i < 2) bar[i] = 0;
}

// W [K_DIM][N] fp32 -> Wt [N][K_DIM] bf16
__global__ __launch_bounds__(256) void wconv_kernel(const float* __restrict__ W,
                                                    u16* __restrict__ Wt, int N) {
  int k = blockIdx.x * 64 + (threadIdx.x & 63);
  int n = blockIdx.y * 4 + (threadIdx.x >> 6);
  Wt[(size_t)n * K_DIM + k] = f2bf(W[(size_t)k * N + n]);
}

__global__ __launch_bounds__(128) void embed_kernel(const int* __restrict__ inp,
                                                    const float* __restrict__ emb,
                                                    u16* __restrict__ X) {
  int rb = blockIdx.x;
  int idx = inp[rb];
  int e = threadIdx.x * 4;
  float4 v = *(const float4*)&emb[(size_t)idx * E_DIM + e];
  ushort4 o;
  o.x = f2bf(v.x); o.y = f2bf(v.y); o.z = f2bf(v.z); o.w = f2bf(v.w);
  *(ushort4*)&X[(size_t)rb * E_DIM + e] = o;
}

// Swizzled LDS weight read: logical [48 cols][1536 k] bf16, row stride 3072 B.
__device__ __forceinline__ bf16x8 ldsW(const u16* Wl, int lc, int k) {
  int ofs = lc * 3072 + k * 2;
  ofs ^= ((lc & 7) << 4);
  return *(const bf16x8*)((const char*)Wl + ofs);
}

// Pure-atomic grid barrier: no cache flushes. Shared data travels via sc0sc1.
__device__ __forceinline__ void grid_barrier(int* cnt, int* gen) {
  __syncthreads();  // s_waitcnt vmcnt(0): all sc-stores acked at coherence point
  if (threadIdx.x == 0) {
    int g = __hip_atomic_load(gen, __ATOMIC_RELAXED, __HIP_MEMORY_SCOPE_AGENT);
    int prev = __hip_atomic_fetch_add(cnt, 1, __ATOMIC_RELAXED, __HIP_MEMORY_SCOPE_AGENT);
    if (prev == NWG - 1) {
      __hip_atomic_store(cnt, 0, __ATOMIC_RELAXED, __HIP_MEMORY_SCOPE_AGENT);
      __hip_atomic_fetch_add(gen, 1, __ATOMIC_RELAXED, __HIP_MEMORY_SCOPE_AGENT);
    } else {
      while (__hip_atomic_load(gen, __ATOMIC_RELAXED, __HIP_MEMORY_SCOPE_AGENT) == g) {
        __builtin_amdgcn_s_sleep(1);
      }
    }
  }
  __syncthreads();
}

// Persistent GRU loop. Grid: 256 WGs x 256 thr.
// WG = (col-tile ct in [0,64)) x (row-quarter mq in [0,4)); rows [mq*64,+64).
// ct owns gate cols [ct*32,+32) and cand cols [ct*16,+16).
// Wave wv owns rows rbase = mq*64 + wv*16.
__global__ void __launch_bounds__(256, 1) gru_loop(
    const u16* __restrict__ X, const u16* __restrict__ WgT,
    const u16* __restrict__ WcT, const float* __restrict__ bg,
    const float* __restrict__ bc, float* __restrict__ hF,
    u16* __restrict__ hB, u16* __restrict__ rhB, float* __restrict__ zb,
    const int* __restrict__ lens, int* bar) {
  __shared__ __align__(16) u16 Wl[48 * K_DIM];  // 147456 B
  const int tid = threadIdx.x;
  const int ct = blockIdx.x >> 2;
  const int mq = blockIdx.x & 3;

  // Stage weights once: 48 cols x 1536 k.
#pragma unroll 4
  for (int it = 0; it < 36; ++it) {
    int ci = it * 256 + tid;
    int lc = ci / 192;
    int k0 = (ci - lc * 192) * 8;
    const u16* src = (lc < 32)
        ? WgT + (size_t)(ct * 32 + lc) * K_DIM + k0
        : WcT + (size_t)(ct * 16 + (lc - 32)) * K_DIM + k0;
    uint4 v = *(const uint4*)src;
    int ofs = lc * 3072 + k0 * 2;
    ofs ^= ((lc & 7) << 4);
    *(uint4*)((char*)Wl + ofs) = v;
  }
  __syncthreads();

  const int lane = tid & 63, wv = tid >> 6;
  const int l15 = lane & 15;
  const int kq8 = (lane >> 4) * 8;
  const int lq4 = (lane >> 4) * 4;
  const int rbase = mq * 64 + wv * 16;
  const u16* Hp = hB + (size_t)(rbase + l15) * U_DIM + kq8;
  const u16* Rp = rhB + (size_t)(rbase + l15) * U_DIM + kq8;
  int* cnt = bar;
  int* gen = bar + 1;

  // Hoisted per-thread constants.
  int len4[4];
#pragma unroll
  for (int q = 0; q < 4; ++q) len4[q] = lens[rbase + lq4 + q];
  const float bg0 = bg[ct * 32 + l15];
  const float bg1 = bg[ct * 32 + 16 + l15];
  const float bc0 = bc[ct * 16 + l15];
  const int nc = ct * 16 + l15;

  bf16x8 af[16], ah[32];
  for (int t = 0; t < T_DIM; ++t) {
    // ---- Phase A: gates = sigmoid([x,h] @ Wg + bg) -> rh, z ----
    // Batched coherent loads: h-frags + (r-WGs) hF for the r*h product.
#pragma unroll
    for (int kb = 0; kb < 32; ++kb) ld16_sc(&ah[kb], Hp + kb * 32);
    float hf[2][4];
    if (ct < 32) {
#pragma unroll
      for (int j = 0; j < 2; ++j)
#pragma unroll
        for (int q = 0; q < 4; ++q)
          ld4f_sc(&hf[j][q],
                  hF + (size_t)(rbase + lq4 + q) * U_DIM + ct * 32 + j * 16 + l15);
    }
    const u16* Xt = X + ((size_t)t * B_DIM + rbase + l15) * E_DIM + kq8;
#pragma unroll
    for (int kb = 0; kb < 16; ++kb) af[kb] = *(const bf16x8*)(Xt + kb * 32);
    WAIT_VM_ALL();

    f32x4 a0 = {0.f, 0.f, 0.f, 0.f}, a1 = {0.f, 0.f, 0.f, 0.f};
#pragma unroll
    for (int kb = 0; kb < 48; ++kb) {
      bf16x8 av = (kb < 16) ? af[kb] : ah[kb - 16];
      bf16x8 b0 = ldsW(Wl, l15, kb * 32 + kq8);
      bf16x8 b1 = ldsW(Wl, 16 + l15, kb * 32 + kq8);
      a0 = __builtin_amdgcn_mfma_f32_16x16x32_bf16(av, b0, a0, 0, 0, 0);
      a1 = __builtin_amdgcn_mfma_f32_16x16x32_bf16(av, b1, a1, 0, 0, 0);
    }
#pragma unroll
    for (int j = 0; j < 2; ++j) {
      f32x4 acc = j ? a1 : a0;
      float bias = j ? bg1 : bg0;
#pragma unroll
      for (int q = 0; q < 4; ++q) {
        int row = rbase + lq4 + q;
        float g = 1.f / (1.f + __expf(-(acc[q] + bias)));
        if (ct < 32) {
          st2_sc(rhB + (size_t)row * U_DIM + ct * 32 + j * 16 + l15,
                 f2bf(g * hf[j][q]));
        } else {
          st4f_sc(zb + (size_t)row * U_DIM + (ct - 32) * 32 + j * 16 + l15, g);
        }
      }
    }
    grid_barrier(cnt, gen);

    // ---- Phase B: cand = tanh([x, rh] @ Wc + bc); h update ----
    // x-frags af[] reused from phase A (same rows, same t).
#pragma unroll
    for (int kb = 0; kb < 32; ++kb) ld16_sc(&ah[kb], Rp + kb * 32);
    float zq[4], hq[4];
#pragma unroll
    for (int q = 0; q < 4; ++q) {
      size_t o = (size_t)(rbase + lq4 + q) * U_DIM + nc;
      ld4f_sc(&zq[q], zb + o);
      ld4f_sc(&hq[q], hF + o);
    }
    WAIT_VM_ALL();

    f32x4 a2 = {0.f, 0.f, 0.f, 0.f};
#pragma unroll
    for (int kb = 0; kb < 48; ++kb) {
      bf16x8 av = (kb < 16) ? af[kb] : ah[kb - 16];
      bf16x8 b2 = ldsW(Wl, 32 + l15, kb * 32 + kq8);
      a2 = __builtin_amdgcn_mfma_f32_16x16x32_bf16(av, b2, a2, 0, 0, 0);
    }
#pragma unroll
    for (int q = 0; q < 4; ++q) {
      int row = rbase + lq4 + q;
      float c = tanhf(a2[q] + bc0);
      float hn = zq[q] * hq[q] + (1.f - zq[q]) * c;
      float v = (t < len4[q]) ? hn : hq[q];
      size_t o = (size_t)row * U_DIM + nc;
      st4f_sc(hF + o, v);
      st2_sc(hB + o, f2bf(v));
    }
    grid_barrier(cnt, gen);
  }
}

__global__ __launch_bounds__(256) void mlp1_kernel(const float* __restrict__ h,
                                                   const float* __restrict__ W1,
                                                   const float* __restrict__ b1,
                                                   float* __restrict__ o1) {
  int m = blockIdx.x, tid = threadIdx.x;
  __shared__ float xs[1024];
  for (int k = tid; k < 1024; k += 256) xs[k] = h[(size_t)m * 1024 + k];
  __syncthreads();
  for (int n = tid; n < 512; n += 256) {
    float s = b1[n];
    for (int k = 0; k < 1024; ++k) s += xs[k] * W1[(size_t)k * 512 + n];
    o1[(size_t)m * 512 + n] = fmaxf(s, 0.f);
  }
}

__global__ __launch_bounds__(256) void mlp2_kernel(const float* __restrict__ x,
                                                   const float* __restrict__ W2,
                                                   const float* __restrict__ b2,
                                                   float* __restrict__ o2) {
  int m = blockIdx.x, tid = threadIdx.x;
  __shared__ float xs[512];
  for (int k = tid; k < 512; k += 256) xs[k] = x[(size_t)m * 512 + k];
  __syncthreads();
  int n = tid;
  float s = b2[n];
  for (int k = 0; k < 512; ++k) s += xs[k] * W2[(size_t)k * 256 + n];
  o2[(size_t)m * 256 + n] = fmaxf(s, 0.f);
}

__global__ __launch_bounds__(256) void mlp3_kernel(const float* __restrict__ x,
                                                   const float* __restrict__ W3,
                                                   const float* __restrict__ b3,
                                                   float* __restrict__ out) {
  int m = blockIdx.x, tid = threadIdx.x;
  float xk = x[(size_t)m * 256 + tid];
  float p0 = xk * W3[tid * 2 + 0];
  float p1 = xk * W3[tid * 2 + 1];
#pragma unroll
  for (int off = 32; off; off >>= 1) {
    p0 += __shfl_down(p0, off);
    p1 += __shfl_down(p1, off);
  }
  __shared__ float s0[4], s1[4];
  int wave = tid >> 6, lane = tid & 63;
  if (lane == 0) { s0[wave] = p0; s1[wave] = p1; }
  __syncthreads();
  if (tid == 0) {
    float l0 = s0[0] + s0[1] + s0[2] + s0[3] + b3[0];
    float l1 = s1[0] + s1[1] + s1[2] + s1[3] + b3[1];
    out[m * 2 + 0] = l0;
    out[m * 2 + 1] = l1;
    float mx = fmaxf(l0, l1);
    float e0 = __expf(l0 - mx), e1 = __expf(l1 - mx);
    float inv = 1.f / (e0 + e1);
    out[512 + m * 2 + 0] = e0 * inv;
    out[512 + m * 2 + 1] = e1 * inv;
  }
}

extern "C" void kernel_launch(void* const* d_in, const int* in_sizes, int n_in,
                              void* d_out, int out_size, void* d_ws, size_t ws_size,
                              hipStream_t stream) {
  (void)in_sizes; (void)n_in; (void)out_size; (void)ws_size;
  const int* inputs = (const int*)d_in[0];
  const int* lens = (const int*)d_in[1];
  const float* embedder = (const float*)d_in[2];
  const float* Wg = (const float*)d_in[3];
  const float* bg = (const float*)d_in[4];
  const float* Wc = (const float*)d_in[5];
  const float* bc = (const float*)d_in[6];
  const float* W1 = (const float*)d_in[7];
  const float* b1 = (const float*)d_in[8];
  const float* W2 = (const float*)d_in[9];
  const float* b2 = (const float*)d_in[10];
  const float* W3 = (const float*)d_in[11];
  const float* b3 = (const float*)d_in[12];
  float* out = (float*)d_out;

  char* ws = (char*)d_ws;
  size_t off = 0;
  u16* X = (u16*)(ws + off);       off += (size_t)T_DIM * B_DIM * E_DIM * 2;
  u16* WgT = (u16*)(ws + off);     off += (size_t)NG * K_DIM * 2;
  u16* WcT = (u16*)(ws + off);     off += (size_t)U_DIM * K_DIM * 2;
  float* hF = (float*)(ws + off);  off += (size_t)B_DIM * U_DIM * 4;
  u16* hB = (u16*)(ws + off);      off += (size_t)B_DIM * U_DIM * 2;
  u16* rhB = (u16*)(ws + off);     off += (size_t)B_DIM * U_DIM * 2;
  float* zb = (float*)(ws + off);  off += (size_t)B_DIM * U_DIM * 4;
  float* o1 = (float*)(ws + off);  off += (size_t)B_DIM * 512 * 4;
  float* o2 = (float*)(ws + off);  off += (size_t)B_DIM * 256 * 4;
  int* bar = (int*)(ws + off);     off += 256;

  init_kernel<<<dim3(1024), dim3(256), 0, stream>>>(hF, hB, bar);
  wconv_kernel<<<dim3(24, 512), dim3(256), 0, stream>>>(Wg, WgT, NG);
  wconv_kernel<<<dim3(24, 256), dim3(256), 0, stream>>>(Wc, WcT, U_DIM);
  embed_kernel<<<dim3(T_DIM * B_DIM), dim3(128), 0, stream>>>(inputs, embedder, X);

  gru_loop<<<dim3(NWG), dim3(256), 0, stream>>>(X, WgT, WcT, bg, bc, hF, hB, rhB,
                                                zb, lens, bar);

  mlp1_kernel<<<dim3(256), dim3(256), 0, stream>>>(hF, W1, b1, o1);
  mlp2_kernel<<<dim3(256), dim3(256), 0, stream>>>(o1, W2, b2, o2);
  mlp3_kernel<<<dim3(256), dim3(256), 0, stream>>>(o2, W3, b3, out);
}

// Round 7
// 14362.794 us; speedup vs baseline: 2.2470x; 1.2370x over previous
//
#include <hip/hip_runtime.h>

typedef unsigned short u16;
typedef unsigned int u32;
typedef unsigned long long u64;

using bf16x8 = __attribute__((ext_vector_type(8))) __bf16;
using f32x4  = __attribute__((ext_vector_type(4))) float;

#define T_DIM 512
#define B_DIM 256
#define E_DIM 512
#define U_DIM 1024
#define K_DIM 1536   /* E+U */
#define NG    2048   /* 2U */
#define NWG   256    /* persistent grid: 1 WG/CU on all 256 CUs */

__device__ __forceinline__ u16 f2bf(float f) {
  union { float f; u32 u; } v; v.f = f;
  return (u16)((v.u + 0x7fffu + ((v.u >> 16) & 1u)) >> 16);
}

// ---- device-coherent cross-WG traffic.
// Loads: compiler-visible agent-scope atomic loads (correct cache bypass,
// correct waitcnts, spill-safe — no inline-asm load hazards).
__device__ __forceinline__ float ld_f32_coh(const float* p) {
  u32 r = __hip_atomic_load((const u32*)p, __ATOMIC_RELAXED,
                            __HIP_MEMORY_SCOPE_AGENT);
  union { u32 u; float f; } c; c.u = r;
  return c.f;
}
__device__ __forceinline__ bf16x8 ld_bf8_coh(const u16* p) {
  union { u64 q[2]; bf16x8 v; } c;
  c.q[0] = __hip_atomic_load((const u64*)p, __ATOMIC_RELAXED,
                             __HIP_MEMORY_SCOPE_AGENT);
  c.q[1] = __hip_atomic_load(((const u64*)p) + 1, __ATOMIC_RELAXED,
                             __HIP_MEMORY_SCOPE_AGENT);
  return c.v;
}
// Stores: RETURNING atomic exchange — vmcnt ack == performed at the LLC
// (the cross-XCD coherence point). The syncthreads vmcnt(0) drain before the
// barrier arrival RMW therefore proves data visibility; plain sc stores ack
// before reaching the LLC and raced (rounds 5/6 failure).
__device__ __forceinline__ void st_u32_coh(u32* p, u32 v) {
  u32 r = __hip_atomic_exchange(p, v, __ATOMIC_RELAXED,
                                __HIP_MEMORY_SCOPE_AGENT);
  asm volatile("" :: "v"(r));  // keep returning form (no DCE to plain store)
}
__device__ __forceinline__ void st_f32_coh(float* p, float v) {
  union { float f; u32 u; } c; c.f = v;
  st_u32_coh((u32*)p, c.u);
}

__global__ __launch_bounds__(256) void init_kernel(float* hF, u16* hB, int* bar) {
  int i = blockIdx.x * 256 + threadIdx.x;
  hF[i] = 0.f;
  hB[i] = 0;
  if (i < 4096) bar[i] = 0;  // 4 groups x 1024 ints of barrier state
}

// W [K_DIM][N] fp32 -> Wt [N][K_DIM] bf16
__global__ __launch_bounds__(256) void wconv_kernel(const float* __restrict__ W,
                                                    u16* __restrict__ Wt, int N) {
  int k = blockIdx.x * 64 + (threadIdx.x & 63);
  int n = blockIdx.y * 4 + (threadIdx.x >> 6);
  Wt[(size_t)n * K_DIM + k] = f2bf(W[(size_t)k * N + n]);
}

__global__ __launch_bounds__(128) void embed_kernel(const int* __restrict__ inp,
                                                    const float* __restrict__ emb,
                                                    u16* __restrict__ X) {
  int rb = blockIdx.x;
  int idx = inp[rb];
  int e = threadIdx.x * 4;
  float4 v = *(const float4*)&emb[(size_t)idx * E_DIM + e];
  ushort4 o;
  o.x = f2bf(v.x); o.y = f2bf(v.y); o.z = f2bf(v.z); o.w = f2bf(v.w);
  *(ushort4*)&X[(size_t)rb * E_DIM + e] = o;
}

// Swizzled LDS weight read: logical [48 cols][1536 k] bf16, row stride 3072 B.
__device__ __forceinline__ bf16x8 ldsW(const u16* Wl, int lc, int k) {
  int ofs = lc * 3072 + k * 2;
  ofs ^= ((lc & 7) << 4);
  return *(const bf16x8*)((const char*)Wl + ofs);
}

// Hierarchical per-group barrier. Group = 64 WGs (one row-quarter mq).
// gbase layout (ints): [0]=gen, [32]=root counter, [64+s*32]=sub counter s.
// Monotonic counters, no resets -> replay-safe (init zeroes each call).
// Data visibility: every cross-WG store is an LLC-acked exchange, drained by
// the syncthreads vmcnt(0) below BEFORE the arrival RMW.
__device__ __forceinline__ void group_barrier(int* gbase, int kidx, int phase) {
  __syncthreads();
  if (threadIdx.x == 0) {
    int* gen = gbase;
    int* root = gbase + 32;
    int* sub = gbase + 64 + (kidx & 7) * 32;
    int prev = __hip_atomic_fetch_add(sub, 1, __ATOMIC_RELAXED,
                                      __HIP_MEMORY_SCOPE_AGENT);
    bool done = false;
    if ((prev & 7) == 7) {  // last of my 8 at the sub-counter
      int rprev = __hip_atomic_fetch_add(root, 1, __ATOMIC_RELAXED,
                                         __HIP_MEMORY_SCOPE_AGENT);
      if ((rprev & 7) == 7) {  // last sub-group: release
        __hip_atomic_fetch_add(gen, 1, __ATOMIC_RELAXED,
                               __HIP_MEMORY_SCOPE_AGENT);
        done = true;
      }
    }
    if (!done) {
      while (__hip_atomic_load(gen, __ATOMIC_RELAXED,
                               __HIP_MEMORY_SCOPE_AGENT) < phase) {
        __builtin_amdgcn_s_sleep(1);
      }
    }
  }
  __syncthreads();
}

// Persistent GRU loop. Grid: 256 WGs x 256 thr.
// WG = (col-tile ct in [0,64)) x (row-quarter mq in [0,4)); rows [mq*64,+64).
// ct owns gate cols [ct*32,+32) and cand cols [ct*16,+16).
// Rows never interact -> each mq is an independent sync domain of 64 WGs.
__global__ void __launch_bounds__(256, 1) gru_loop(
    const u16* __restrict__ X, const u16* __restrict__ WgT,
    const u16* __restrict__ WcT, const float* __restrict__ bg,
    const float* __restrict__ bc, float* __restrict__ hF,
    u16* __restrict__ hB, u16* __restrict__ rhB, float* __restrict__ zb,
    const int* __restrict__ lens, int* bar) {
  __shared__ __align__(16) u16 Wl[48 * K_DIM];  // 147456 B
  const int tid = threadIdx.x;
  const int wgid = blockIdx.x;
  const int ct = wgid >> 2;
  const int mq = wgid & 3;

  // Stage weights once: 48 cols x 1536 k.
#pragma unroll 4
  for (int it = 0; it < 36; ++it) {
    int ci = it * 256 + tid;
    int lc = ci / 192;
    int k0 = (ci - lc * 192) * 8;
    const u16* src = (lc < 32)
        ? WgT + (size_t)(ct * 32 + lc) * K_DIM + k0
        : WcT + (size_t)(ct * 16 + (lc - 32)) * K_DIM + k0;
    uint4 v = *(const uint4*)src;
    int ofs = lc * 3072 + k0 * 2;
    ofs ^= ((lc & 7) << 4);
    *(uint4*)((char*)Wl + ofs) = v;
  }
  __syncthreads();

  const int lane = tid & 63, wv = tid >> 6;
  const int l15 = lane & 15;
  const int kq8 = (lane >> 4) * 8;
  const int lq4 = (lane >> 4) * 4;
  const int rbase = mq * 64 + wv * 16;
  const u16* Hp = hB + (size_t)(rbase + l15) * U_DIM + kq8;
  const u16* Rp = rhB + (size_t)(rbase + l15) * U_DIM + kq8;
  int* gbase = bar + mq * 1024;

  // Hoisted per-thread constants.
  int len4[4];
#pragma unroll
  for (int q = 0; q < 4; ++q) len4[q] = lens[rbase + lq4 + q];
  const float bg0 = bg[ct * 32 + l15];
  const float bg1 = bg[ct * 32 + 16 + l15];
  const float bc0 = bc[ct * 16 + l15];
  const int nc = ct * 16 + l15;

  bf16x8 af[16], ah[32];
  int phase = 0;
  for (int t = 0; t < T_DIM; ++t) {
    // ---- Phase A: gates = sigmoid([x,h] @ Wg + bg) -> rh, z ----
#pragma unroll
    for (int kb = 0; kb < 32; ++kb) ah[kb] = ld_bf8_coh(Hp + kb * 32);
    float hf[2][4];
    if (ct < 32) {
#pragma unroll
      for (int j = 0; j < 2; ++j)
#pragma unroll
        for (int q = 0; q < 4; ++q)
          hf[j][q] = ld_f32_coh(
              hF + (size_t)(rbase + lq4 + q) * U_DIM + ct * 32 + j * 16 + l15);
    }
    const u16* Xt = X + ((size_t)t * B_DIM + rbase + l15) * E_DIM + kq8;
#pragma unroll
    for (int kb = 0; kb < 16; ++kb) af[kb] = *(const bf16x8*)(Xt + kb * 32);

    f32x4 a0 = {0.f, 0.f, 0.f, 0.f}, a1 = {0.f, 0.f, 0.f, 0.f};
#pragma unroll
    for (int kb = 0; kb < 48; ++kb) {
      bf16x8 av = (kb < 16) ? af[kb] : ah[kb - 16];
      bf16x8 b0 = ldsW(Wl, l15, kb * 32 + kq8);
      bf16x8 b1 = ldsW(Wl, 16 + l15, kb * 32 + kq8);
      a0 = __builtin_amdgcn_mfma_f32_16x16x32_bf16(av, b0, a0, 0, 0, 0);
      a1 = __builtin_amdgcn_mfma_f32_16x16x32_bf16(av, b1, a1, 0, 0, 0);
    }
#pragma unroll
    for (int j = 0; j < 2; ++j) {
      f32x4 acc = j ? a1 : a0;
      float bias = j ? bg1 : bg0;
#pragma unroll
      for (int q = 0; q < 4; ++q) {
        int row = rbase + lq4 + q;
        float g = 1.f / (1.f + __expf(-(acc[q] + bias)));
        if (ct < 32) {  // r half -> rh bf16, packed pairwise into u32 exchanges
          u16 rv = f2bf(g * hf[j][q]);
          u16 pv = (u16)__shfl_xor((int)rv, 1);
          if (!(lane & 1)) {
            u32 packed = (u32)rv | ((u32)pv << 16);
            st_u32_coh((u32*)(rhB + (size_t)row * U_DIM + ct * 32 + j * 16 + l15),
                       packed);
          }
        } else {        // z half
          st_f32_coh(zb + (size_t)row * U_DIM + (ct - 32) * 32 + j * 16 + l15, g);
        }
      }
    }
    group_barrier(gbase, ct, ++phase);

    // ---- Phase B: cand = tanh([x, rh] @ Wc + bc); h update ----
    // x-frags af[] reused from phase A (same rows, same t).
#pragma unroll
    for (int kb = 0; kb < 32; ++kb) ah[kb] = ld_bf8_coh(Rp + kb * 32);
    float zq[4], hq[4];
#pragma unroll
    for (int q = 0; q < 4; ++q) {
      size_t o = (size_t)(rbase + lq4 + q) * U_DIM + nc;
      zq[q] = ld_f32_coh(zb + o);
      hq[q] = ld_f32_coh(hF + o);
    }

    f32x4 a2 = {0.f, 0.f, 0.f, 0.f};
#pragma unroll
    for (int kb = 0; kb < 48; ++kb) {
      bf16x8 av = (kb < 16) ? af[kb] : ah[kb - 16];
      bf16x8 b2 = ldsW(Wl, 32 + l15, kb * 32 + kq8);
      a2 = __builtin_amdgcn_mfma_f32_16x16x32_bf16(av, b2, a2, 0, 0, 0);
    }
#pragma unroll
    for (int q = 0; q < 4; ++q) {
      int row = rbase + lq4 + q;
      float c = tanhf(a2[q] + bc0);
      float hn = zq[q] * hq[q] + (1.f - zq[q]) * c;
      float v = (t < len4[q]) ? hn : hq[q];
      st_f32_coh(hF + (size_t)row * U_DIM + nc, v);
      u16 hv = f2bf(v);
      u16 pv = (u16)__shfl_xor((int)hv, 1);
      if (!(lane & 1)) {
        st_u32_coh((u32*)(hB + (size_t)row * U_DIM + nc),
                   (u32)hv | ((u32)pv << 16));
      }
    }
    group_barrier(gbase, ct, ++phase);
  }
}

__global__ __launch_bounds__(256) void mlp1_kernel(const float* __restrict__ h,
                                                   const float* __restrict__ W1,
                                                   const float* __restrict__ b1,
                                                   float* __restrict__ o1) {
  int m = blockIdx.x, tid = threadIdx.x;
  __shared__ float xs[1024];
  for (int k = tid; k < 1024; k += 256) xs[k] = h[(size_t)m * 1024 + k];
  __syncthreads();
  for (int n = tid; n < 512; n += 256) {
    float s = b1[n];
    for (int k = 0; k < 1024; ++k) s += xs[k] * W1[(size_t)k * 512 + n];
    o1[(size_t)m * 512 + n] = fmaxf(s, 0.f);
  }
}

__global__ __launch_bounds__(256) void mlp2_kernel(const float* __restrict__ x,
                                                   const float* __restrict__ W2,
                                                   const float* __restrict__ b2,
                                                   float* __restrict__ o2) {
  int m = blockIdx.x, tid = threadIdx.x;
  __shared__ float xs[512];
  for (int k = tid; k < 512; k += 256) xs[k] = x[(size_t)m * 512 + k];
  __syncthreads();
  int n = tid;
  float s = b2[n];
  for (int k = 0; k < 512; ++k) s += xs[k] * W2[(size_t)k * 256 + n];
  o2[(size_t)m * 256 + n] = fmaxf(s, 0.f);
}

__global__ __launch_bounds__(256) void mlp3_kernel(const float* __restrict__ x,
                                                   const float* __restrict__ W3,
                                                   const float* __restrict__ b3,
                                                   float* __restrict__ out) {
  int m = blockIdx.x, tid = threadIdx.x;
  float xk = x[(size_t)m * 256 + tid];
  float p0 = xk * W3[tid * 2 + 0];
  float p1 = xk * W3[tid * 2 + 1];
#pragma unroll
  for (int off = 32; off; off >>= 1) {
    p0 += __shfl_down(p0, off);
    p1 += __shfl_down(p1, off);
  }
  __shared__ float s0[4], s1[4];
  int wave = tid >> 6, lane = tid & 63;
  if (lane == 0) { s0[wave] = p0; s1[wave] = p1; }
  __syncthreads();
  if (tid == 0) {
    float l0 = s0[0] + s0[1] + s0[2] + s0[3] + b3[0];
    float l1 = s1[0] + s1[1] + s1[2] + s1[3] + b3[1];
    out[m * 2 + 0] = l0;
    out[m * 2 + 1] = l1;
    float mx = fmaxf(l0, l1);
    float e0 = __expf(l0 - mx), e1 = __expf(l1 - mx);
    float inv = 1.f / (e0 + e1);
    out[512 + m * 2 + 0] = e0 * inv;
    out[512 + m * 2 + 1] = e1 * inv;
  }
}

extern "C" void kernel_launch(void* const* d_in, const int* in_sizes, int n_in,
                              void* d_out, int out_size, void* d_ws, size_t ws_size,
                              hipStream_t stream) {
  (void)in_sizes; (void)n_in; (void)out_size; (void)ws_size;
  const int* inputs = (const int*)d_in[0];
  const int* lens = (const int*)d_in[1];
  const float* embedder = (const float*)d_in[2];
  const float* Wg = (const float*)d_in[3];
  const float* bg = (const float*)d_in[4];
  const float* Wc = (const float*)d_in[5];
  const float* bc = (const float*)d_in[6];
  const float* W1 = (const float*)d_in[7];
  const float* b1 = (const float*)d_in[8];
  const float* W2 = (const float*)d_in[9];
  const float* b2 = (const float*)d_in[10];
  const float* W3 = (const float*)d_in[11];
  const float* b3 = (const float*)d_in[12];
  float* out = (float*)d_out;

  char* ws = (char*)d_ws;
  size_t off = 0;
  u16* X = (u16*)(ws + off);       off += (size_t)T_DIM * B_DIM * E_DIM * 2;
  u16* WgT = (u16*)(ws + off);     off += (size_t)NG * K_DIM * 2;
  u16* WcT = (u16*)(ws + off);     off += (size_t)U_DIM * K_DIM * 2;
  float* hF = (float*)(ws + off);  off += (size_t)B_DIM * U_DIM * 4;
  u16* hB = (u16*)(ws + off);      off += (size_t)B_DIM * U_DIM * 2;
  u16* rhB = (u16*)(ws + off);     off += (size_t)B_DIM * U_DIM * 2;
  float* zb = (float*)(ws + off);  off += (size_t)B_DIM * U_DIM * 4;
  float* o1 = (float*)(ws + off);  off += (size_t)B_DIM * 512 * 4;
  float* o2 = (float*)(ws + off);  off += (size_t)B_DIM * 256 * 4;
  int* bar = (int*)(ws + off);     off += 65536;

  init_kernel<<<dim3(1024), dim3(256), 0, stream>>>(hF, hB, bar);
  wconv_kernel<<<dim3(24, 512), dim3(256), 0, stream>>>(Wg, WgT, NG);
  wconv_kernel<<<dim3(24, 256), dim3(256), 0, stream>>>(Wc, WcT, U_DIM);
  embed_kernel<<<dim3(T_DIM * B_DIM), dim3(128), 0, stream>>>(inputs, embedder, X);

  gru_loop<<<dim3(NWG), dim3(256), 0, stream>>>(X, WgT, WcT, bg, bc, hF, hB, rhB,
                                                zb, lens, bar);

  mlp1_kernel<<<dim3(256), dim3(256), 0, stream>>>(hF, W1, b1, o1);
  mlp2_kernel<<<dim3(256), dim3(256), 0, stream>>>(o1, W2, b2, o2);
  mlp3_kernel<<<dim3(256), dim3(256), 0, stream>>>(o2, W3, b3, out);
}

// Round 9
// 13740.770 us; speedup vs baseline: 2.3487x; 1.0453x over previous
//
#include <hip/hip_runtime.h>

typedef unsigned short u16;
typedef unsigned int u32;
typedef unsigned long long u64;

using bf16x8 = __attribute__((ext_vector_type(8))) __bf16;
using f32x4  = __attribute__((ext_vector_type(4))) float;

#define T_DIM 512
#define B_DIM 256
#define E_DIM 512
#define U_DIM 1024
#define K_DIM 1536   /* E+U */
#define NG    2048   /* 2U */
#define NWG   256    /* persistent grid: 1 WG/CU on all 256 CUs */

__device__ __forceinline__ u16 f2bf(float f) {
  union { float f; u32 u; } v; v.f = f;
  return (u16)((v.u + 0x7fffu + ((v.u >> 16) & 1u)) >> 16);
}

// ---- device-coherent cross-WG traffic (ALL r7-proven mechanisms).
// LOADS: compiler-visible agent-scope atomic loads. NEVER inline-asm loads:
// asm loads have no modeled memory dep and get hoisted above the barrier's
// atomic spin (r5/r6/r8 corruption). Atomic loads are ordered wrt atomics and
// still batch-issue (all outstanding, one waitcnt before first use).
__device__ __forceinline__ float ld_f32_coh(const float* p) {
  u32 r = __hip_atomic_load((const u32*)p, __ATOMIC_RELAXED,
                            __HIP_MEMORY_SCOPE_AGENT);
  union { u32 u; float f; } c; c.u = r;
  return c.f;
}
__device__ __forceinline__ bf16x8 ld_bf8_coh(const u16* p) {
  union { u64 q[2]; bf16x8 v; } c;
  c.q[0] = __hip_atomic_load((const u64*)p, __ATOMIC_RELAXED,
                             __HIP_MEMORY_SCOPE_AGENT);
  c.q[1] = __hip_atomic_load(((const u64*)p) + 1, __ATOMIC_RELAXED,
                             __HIP_MEMORY_SCOPE_AGENT);
  return c.v;
}
// STORES: RETURNING atomic exchange — vmcnt ack == performed at the LLC
// (cross-XCD coherence point). The syncthreads vmcnt(0) drain before the
// arrival flag therefore proves data visibility (plain sc stores ack early
// and raced in r5/r6).
__device__ __forceinline__ void st_u32_coh(u32* p, u32 v) {
  u32 r = __hip_atomic_exchange(p, v, __ATOMIC_RELAXED,
                                __HIP_MEMORY_SCOPE_AGENT);
  asm volatile("" :: "v"(r));  // keep returning form (no DCE to plain store)
}
__device__ __forceinline__ void st_f32_coh(float* p, float v) {
  union { float f; u32 u; } c; c.f = v;
  st_u32_coh((u32*)p, c.u);
}

__global__ __launch_bounds__(256) void init_kernel(float* hF, u16* hB, int* bar) {
  int i = blockIdx.x * 256 + threadIdx.x;
  hF[i] = 0.f;
  hB[i] = 0;
  if (i < 8192) bar[i] = 0;  // 4 domains x 2048 ints of flag state
}

// W [K_DIM][N] fp32 -> Wt [N][K_DIM] bf16
__global__ __launch_bounds__(256) void wconv_kernel(const float* __restrict__ W,
                                                    u16* __restrict__ Wt, int N) {
  int k = blockIdx.x * 64 + (threadIdx.x & 63);
  int n = blockIdx.y * 4 + (threadIdx.x >> 6);
  Wt[(size_t)n * K_DIM + k] = f2bf(W[(size_t)k * N + n]);
}

__global__ __launch_bounds__(128) void embed_kernel(const int* __restrict__ inp,
                                                    const float* __restrict__ emb,
                                                    u16* __restrict__ X) {
  int rb = blockIdx.x;
  int idx = inp[rb];
  int e = threadIdx.x * 4;
  float4 v = *(const float4*)&emb[(size_t)idx * E_DIM + e];
  ushort4 o;
  o.x = f2bf(v.x); o.y = f2bf(v.y); o.z = f2bf(v.z); o.w = f2bf(v.w);
  *(ushort4*)&X[(size_t)rb * E_DIM + e] = o;
}

// Swizzled LDS weight read: logical [48 cols][1536 k] bf16, row stride 3072 B.
__device__ __forceinline__ bf16x8 ldsW(const u16* Wl, int lc, int k) {
  int ofs = lc * 3072 + k * 2;
  ofs ^= ((lc & 7) << 4);
  return *(const bf16x8*)((const char*)Wl + ofs);
}

// Flag-poll group barrier (domain = 64 WGs of one row-quarter mq).
// fbase[w*32] = arrival flag of domain-WG w (128 B apart -> parallel stores,
// no same-line RMW serialization). Every WG detects directly: wave 0 lane w
// spins on flag w (divergent-exit loop, reconverges when all 64 arrived).
// No gen counter, no aggregator hop. Monotonic phases; init zeroes per call.
__device__ __forceinline__ void group_barrier(int* fbase, int ct, int phase) {
  __syncthreads();  // per-wave vmcnt(0): all exchange-stores LLC-acked
  if (threadIdx.x < 64) {
    if (threadIdx.x == 0) {
      int r = __hip_atomic_exchange(&fbase[ct * 32], phase, __ATOMIC_RELAXED,
                                    __HIP_MEMORY_SCOPE_AGENT);
      asm volatile("" :: "v"(r));
    }
    while (__hip_atomic_load(&fbase[threadIdx.x * 32], __ATOMIC_RELAXED,
                             __HIP_MEMORY_SCOPE_AGENT) < phase) {
      __builtin_amdgcn_s_sleep(1);
    }
  }
  __syncthreads();
}

// Persistent GRU loop. Grid: 256 WGs x 256 thr.
// WG = (col-tile ct in [0,64)) x (row-quarter mq in [0,4)); rows [mq*64,+64).
// ct owns gate cols [ct*32,+32) and cand cols [ct*16,+16).
// Rows never interact -> each mq is an independent sync domain of 64 WGs.
__global__ void __launch_bounds__(256, 1) gru_loop(
    const u16* __restrict__ X, const u16* __restrict__ WgT,
    const u16* __restrict__ WcT, const float* __restrict__ bg,
    const float* __restrict__ bc, float* __restrict__ hF,
    u16* __restrict__ hB, u16* __restrict__ rhB, float* __restrict__ zb,
    const int* __restrict__ lens, int* bar) {
  __shared__ __align__(16) u16 Wl[48 * K_DIM];  // 147456 B
  const int tid = threadIdx.x;
  const int wgid = blockIdx.x;
  const int ct = wgid >> 2;
  const int mq = wgid & 3;

  // Stage weights once: 48 cols x 1536 k.
#pragma unroll 4
  for (int it = 0; it < 36; ++it) {
    int ci = it * 256 + tid;
    int lc = ci / 192;
    int k0 = (ci - lc * 192) * 8;
    const u16* src = (lc < 32)
        ? WgT + (size_t)(ct * 32 + lc) * K_DIM + k0
        : WcT + (size_t)(ct * 16 + (lc - 32)) * K_DIM + k0;
    uint4 v = *(const uint4*)src;
    int ofs = lc * 3072 + k0 * 2;
    ofs ^= ((lc & 7) << 4);
    *(uint4*)((char*)Wl + ofs) = v;
  }
  __syncthreads();

  const int lane = tid & 63, wv = tid >> 6;
  const int l15 = lane & 15;
  const int kq8 = (lane >> 4) * 8;
  const int lq4 = (lane >> 4) * 4;
  const int rbase = mq * 64 + wv * 16;
  const u16* Hp = hB + (size_t)(rbase + l15) * U_DIM + kq8;
  const u16* Rp = rhB + (size_t)(rbase + l15) * U_DIM + kq8;
  int* fbase = bar + mq * 2048;

  // Hoisted per-thread constants.
  int len4[4];
#pragma unroll
  for (int q = 0; q < 4; ++q) len4[q] = lens[rbase + lq4 + q];
  const float bg0 = bg[ct * 32 + l15];
  const float bg1 = bg[ct * 32 + 16 + l15];
  const float bc0 = bc[ct * 16 + l15];
  const int nc = ct * 16 + l15;

  bf16x8 af[16], ah[32];
  int phase = 0;
  for (int t = 0; t < T_DIM; ++t) {
    // ---- Phase A: gates = sigmoid([x,h] @ Wg + bg) -> rh, z ----
#pragma unroll
    for (int kb = 0; kb < 32; ++kb) ah[kb] = ld_bf8_coh(Hp + kb * 32);
    float hf[2][4];
    if (ct < 32) {
#pragma unroll
      for (int j = 0; j < 2; ++j)
#pragma unroll
        for (int q = 0; q < 4; ++q)
          hf[j][q] = ld_f32_coh(
              hF + (size_t)(rbase + lq4 + q) * U_DIM + ct * 32 + j * 16 + l15);
    }
    const u16* Xt = X + ((size_t)t * B_DIM + rbase + l15) * E_DIM + kq8;
#pragma unroll
    for (int kb = 0; kb < 16; ++kb) af[kb] = *(const bf16x8*)(Xt + kb * 32);

    f32x4 a0 = {0.f, 0.f, 0.f, 0.f}, a1 = {0.f, 0.f, 0.f, 0.f};
#pragma unroll
    for (int kb = 0; kb < 48; ++kb) {
      bf16x8 av = (kb < 16) ? af[kb] : ah[kb - 16];
      bf16x8 b0 = ldsW(Wl, l15, kb * 32 + kq8);
      bf16x8 b1 = ldsW(Wl, 16 + l15, kb * 32 + kq8);
      a0 = __builtin_amdgcn_mfma_f32_16x16x32_bf16(av, b0, a0, 0, 0, 0);
      a1 = __builtin_amdgcn_mfma_f32_16x16x32_bf16(av, b1, a1, 0, 0, 0);
    }
#pragma unroll
    for (int j = 0; j < 2; ++j) {
      f32x4 acc = j ? a1 : a0;
      float bias = j ? bg1 : bg0;
#pragma unroll
      for (int q = 0; q < 4; ++q) {
        int row = rbase + lq4 + q;
        float g = 1.f / (1.f + __expf(-(acc[q] + bias)));
        if (ct < 32) {  // r half -> rh bf16, packed pairwise into u32 exchanges
          u16 rv = f2bf(g * hf[j][q]);
          u16 pv = (u16)__shfl_xor((int)rv, 1);
          if (!(lane & 1)) {
            u32 packed = (u32)rv | ((u32)pv << 16);
            st_u32_coh((u32*)(rhB + (size_t)row * U_DIM + ct * 32 + j * 16 + l15),
                       packed);
          }
        } else {        // z half
          st_f32_coh(zb + (size_t)row * U_DIM + (ct - 32) * 32 + j * 16 + l15, g);
        }
      }
    }
    // Phase-B x-part: reads only af (own regs) + LDS weights — no cross-WG
    // data, safe to compute before the barrier (overlaps arrival latency).
    f32x4 a2 = {0.f, 0.f, 0.f, 0.f};
#pragma unroll
    for (int kb = 0; kb < 16; ++kb) {
      bf16x8 b2 = ldsW(Wl, 32 + l15, kb * 32 + kq8);
      a2 = __builtin_amdgcn_mfma_f32_16x16x32_bf16(af[kb], b2, a2, 0, 0, 0);
    }
    group_barrier(fbase, ct, ++phase);

    // ---- Phase B: cand = tanh([x, rh] @ Wc + bc); h update ----
#pragma unroll
    for (int kb = 0; kb < 32; ++kb) ah[kb] = ld_bf8_coh(Rp + kb * 32);
    float zq[4], hq[4];
#pragma unroll
    for (int q = 0; q < 4; ++q) {
      size_t o = (size_t)(rbase + lq4 + q) * U_DIM + nc;
      zq[q] = ld_f32_coh(zb + o);
      hq[q] = ld_f32_coh(hF + o);
    }

#pragma unroll
    for (int kb = 0; kb < 32; ++kb) {
      bf16x8 b2 = ldsW(Wl, 32 + l15, (kb + 16) * 32 + kq8);
      a2 = __builtin_amdgcn_mfma_f32_16x16x32_bf16(ah[kb], b2, a2, 0, 0, 0);
    }
#pragma unroll
    for (int q = 0; q < 4; ++q) {
      int row = rbase + lq4 + q;
      float c = tanhf(a2[q] + bc0);
      float hn = zq[q] * hq[q] + (1.f - zq[q]) * c;
      float v = (t < len4[q]) ? hn : hq[q];
      st_f32_coh(hF + (size_t)row * U_DIM + nc, v);
      u16 hv = f2bf(v);
      u16 pv = (u16)__shfl_xor((int)hv, 1);
      if (!(lane & 1)) {
        st_u32_coh((u32*)(hB + (size_t)row * U_DIM + nc),
                   (u32)hv | ((u32)pv << 16));
      }
    }
    group_barrier(fbase, ct, ++phase);
  }
}

__global__ __launch_bounds__(256) void mlp1_kernel(const float* __restrict__ h,
                                                   const float* __restrict__ W1,
                                                   const float* __restrict__ b1,
                                                   float* __restrict__ o1) {
  int m = blockIdx.x, tid = threadIdx.x;
  __shared__ float xs[1024];
  for (int k = tid; k < 1024; k += 256) xs[k] = h[(size_t)m * 1024 + k];
  __syncthreads();
  for (int n = tid; n < 512; n += 256) {
    float s = b1[n];
    for (int k = 0; k < 1024; ++k) s += xs[k] * W1[(size_t)k * 512 + n];
    o1[(size_t)m * 512 + n] = fmaxf(s, 0.f);
  }
}

__global__ __launch_bounds__(256) void mlp2_kernel(const float* __restrict__ x,
                                                   const float* __restrict__ W2,
                                                   const float* __restrict__ b2,
                                                   float* __restrict__ o2) {
  int m = blockIdx.x, tid = threadIdx.x;
  __shared__ float xs[512];
  for (int k = tid; k < 512; k += 256) xs[k] = x[(size_t)m * 512 + k];
  __syncthreads();
  int n = tid;
  float s = b2[n];
  for (int k = 0; k < 512; ++k) s += xs[k] * W2[(size_t)k * 256 + n];
  o2[(size_t)m * 256 + n] = fmaxf(s, 0.f);
}

__global__ __launch_bounds__(256) void mlp3_kernel(const float* __restrict__ x,
                                                   const float* __restrict__ W3,
                                                   const float* __restrict__ b3,
                                                   float* __restrict__ out) {
  int m = blockIdx.x, tid = threadIdx.x;
  float xk = x[(size_t)m * 256 + tid];
  float p0 = xk * W3[tid * 2 + 0];
  float p1 = xk * W3[tid * 2 + 1];
#pragma unroll
  for (int off = 32; off; off >>= 1) {
    p0 += __shfl_down(p0, off);
    p1 += __shfl_down(p1, off);
  }
  __shared__ float s0[4], s1[4];
  int wave = tid >> 6, lane = tid & 63;
  if (lane == 0) { s0[wave] = p0; s1[wave] = p1; }
  __syncthreads();
  if (tid == 0) {
    float l0 = s0[0] + s0[1] + s0[2] + s0[3] + b3[0];
    float l1 = s1[0] + s1[1] + s1[2] + s1[3] + b3[1];
    out[m * 2 + 0] = l0;
    out[m * 2 + 1] = l1;
    float mx = fmaxf(l0, l1);
    float e0 = __expf(l0 - mx), e1 = __expf(l1 - mx);
    float inv = 1.f / (e0 + e1);
    out[512 + m * 2 + 0] = e0 * inv;
    out[512 + m * 2 + 1] = e1 * inv;
  }
}

extern "C" void kernel_launch(void* const* d_in, const int* in_sizes, int n_in,
                              void* d_out, int out_size, void* d_ws, size_t ws_size,
                              hipStream_t stream) {
  (void)in_sizes; (void)n_in; (void)out_size; (void)ws_size;
  const int* inputs = (const int*)d_in[0];
  const int* lens = (const int*)d_in[1];
  const float* embedder = (const float*)d_in[2];
  const float* Wg = (const float*)d_in[3];
  const float* bg = (const float*)d_in[4];
  const float* Wc = (const float*)d_in[5];
  const float* bc = (const float*)d_in[6];
  const float* W1 = (const float*)d_in[7];
  const float* b1 = (const float*)d_in[8];
  const float* W2 = (const float*)d_in[9];
  const float* b2 = (const float*)d_in[10];
  const float* W3 = (const float*)d_in[11];
  const float* b3 = (const float*)d_in[12];
  float* out = (float*)d_out;

  char* ws = (char*)d_ws;
  size_t off = 0;
  u16* X = (u16*)(ws + off);       off += (size_t)T_DIM * B_DIM * E_DIM * 2;
  u16* WgT = (u16*)(ws + off);     off += (size_t)NG * K_DIM * 2;
  u16* WcT = (u16*)(ws + off);     off += (size_t)U_DIM * K_DIM * 2;
  float* hF = (float*)(ws + off);  off += (size_t)B_DIM * U_DIM * 4;
  u16* hB = (u16*)(ws + off);      off += (size_t)B_DIM * U_DIM * 2;
  u16* rhB = (u16*)(ws + off);     off += (size_t)B_DIM * U_DIM * 2;
  float* zb = (float*)(ws + off);  off += (size_t)B_DIM * U_DIM * 4;
  float* o1 = (float*)(ws + off);  off += (size_t)B_DIM * 512 * 4;
  float* o2 = (float*)(ws + off);  off += (size_t)B_DIM * 256 * 4;
  int* bar = (int*)(ws + off);     off += 65536;

  init_kernel<<<dim3(1024), dim3(256), 0, stream>>>(hF, hB, bar);
  wconv_kernel<<<dim3(24, 512), dim3(256), 0, stream>>>(Wg, WgT, NG);
  wconv_kernel<<<dim3(24, 256), dim3(256), 0, stream>>>(Wc, WcT, U_DIM);
  embed_kernel<<<dim3(T_DIM * B_DIM), dim3(128), 0, stream>>>(inputs, embedder, X);

  gru_loop<<<dim3(NWG), dim3(256), 0, stream>>>(X, WgT, WcT, bg, bc, hF, hB, rhB,
                                                zb, lens, bar);

  mlp1_kernel<<<dim3(256), dim3(256), 0, stream>>>(hF, W1, b1, o1);
  mlp2_kernel<<<dim3(256), dim3(256), 0, stream>>>(o1, W2, b2, o2);
  mlp3_kernel<<<dim3(256), dim3(256), 0, stream>>>(o2, W3, b3, out);
}

// Round 10
// 12277.287 us; speedup vs baseline: 2.6287x; 1.1192x over previous
//
#include <hip/hip_runtime.h>

typedef unsigned short u16;
typedef unsigned int u32;
typedef unsigned long long u64;

using bf16x8 = __attribute__((ext_vector_type(8))) __bf16;
using f32x4  = __attribute__((ext_vector_type(4))) float;

#define T_DIM 512
#define B_DIM 256
#define E_DIM 512
#define U_DIM 1024
#define K_DIM 1536   /* E+U */
#define NG    2048   /* 2U */
#define NWG   256    /* persistent grid: 1 WG/CU on all 256 CUs */

__device__ __forceinline__ u16 f2bf(float f) {
  union { float f; u32 u; } v; v.f = f;
  return (u16)((v.u + 0x7fffu + ((v.u >> 16) & 1u)) >> 16);
}

// ---- device-coherent cross-WG traffic (r7/r9-proven mechanisms).
// LOADS: compiler-visible agent-scope atomic loads. NEVER inline-asm loads:
// asm loads have no modeled memory dep and get hoisted above the barrier's
// atomic spin (r5/r6/r8 corruption).
__device__ __forceinline__ bf16x8 ld_bf8_coh(const u16* p) {
  union { u64 q[2]; bf16x8 v; } c;
  c.q[0] = __hip_atomic_load((const u64*)p, __ATOMIC_RELAXED,
                             __HIP_MEMORY_SCOPE_AGENT);
  c.q[1] = __hip_atomic_load(((const u64*)p) + 1, __ATOMIC_RELAXED,
                             __HIP_MEMORY_SCOPE_AGENT);
  return c.v;
}
// STORES: RETURNING atomic exchange — vmcnt ack == performed at the LLC
// (cross-XCD coherence point). The syncthreads vmcnt(0) drain before the
// arrival flag therefore proves data visibility (plain sc stores ack early
// and raced in r5/r6). u64 granularity: 4 bf16 per transaction.
__device__ __forceinline__ void st_u64_coh(u64* p, u64 v) {
  u64 r = __hip_atomic_exchange(p, v, __ATOMIC_RELAXED,
                                __HIP_MEMORY_SCOPE_AGENT);
  asm volatile("" :: "v"(r));  // keep returning form (no DCE to plain store)
}

__global__ __launch_bounds__(256) void init_kernel(float* hF, u16* hB, int* bar) {
  int i = blockIdx.x * 256 + threadIdx.x;
  hF[i] = 0.f;
  hB[i] = 0;
  if (i < 8192) bar[i] = 0;  // 4 domains x 2048 ints of flag state
}

// W [K_DIM][N] fp32 -> Wt [N][K_DIM] bf16
__global__ __launch_bounds__(256) void wconv_kernel(const float* __restrict__ W,
                                                    u16* __restrict__ Wt, int N) {
  int k = blockIdx.x * 64 + (threadIdx.x & 63);
  int n = blockIdx.y * 4 + (threadIdx.x >> 6);
  Wt[(size_t)n * K_DIM + k] = f2bf(W[(size_t)k * N + n]);
}

__global__ __launch_bounds__(128) void embed_kernel(const int* __restrict__ inp,
                                                    const float* __restrict__ emb,
                                                    u16* __restrict__ X) {
  int rb = blockIdx.x;
  int idx = inp[rb];
  int e = threadIdx.x * 4;
  float4 v = *(const float4*)&emb[(size_t)idx * E_DIM + e];
  ushort4 o;
  o.x = f2bf(v.x); o.y = f2bf(v.y); o.z = f2bf(v.z); o.w = f2bf(v.w);
  *(ushort4*)&X[(size_t)rb * E_DIM + e] = o;
}

// Swizzled LDS weight read: logical [48 cols][1536 k] bf16, row stride 3072 B.
__device__ __forceinline__ bf16x8 ldsW(const u16* Wl, int lc, int k) {
  int ofs = lc * 3072 + k * 2;
  ofs ^= ((lc & 7) << 4);
  return *(const bf16x8*)((const char*)Wl + ofs);
}

// Flag-poll group barrier (domain = 64 WGs of one row-quarter mq) — r9-proven.
__device__ __forceinline__ void group_barrier(int* fbase, int ct, int phase) {
  __syncthreads();  // per-wave vmcnt(0): all exchange-stores LLC-acked
  if (threadIdx.x < 64) {
    if (threadIdx.x == 0) {
      int r = __hip_atomic_exchange(&fbase[ct * 32], phase, __ATOMIC_RELAXED,
                                    __HIP_MEMORY_SCOPE_AGENT);
      asm volatile("" :: "v"(r));
    }
    while (__hip_atomic_load(&fbase[threadIdx.x * 32], __ATOMIC_RELAXED,
                             __HIP_MEMORY_SCOPE_AGENT) < phase) {
      __builtin_amdgcn_s_sleep(1);
    }
  }
  __syncthreads();
}

// Persistent GRU loop. Grid: 256 WGs x 256 thr.
// WG = (col-tile ct in [0,64)) x (row-quarter mq in [0,4)); rows [mq*64,+64).
// NEW ownership: ct owns gate cols [ct*16,+16) (r-half) AND
// [1024+ct*16,+16) (z-half) AND cand cols [ct*16,+16). With the MFMA C/D
// layout, r/z/c/h for (row, col ct*16+l15) all land in the SAME thread:
// z and the fp32 h master live in REGISTERS (no zb/hF round-trips); only
// rh (phase A) and h-bf16 (phase B) cross WGs, packed 4 bf16 per u64.
__global__ void __launch_bounds__(256, 1) gru_loop(
    const u16* __restrict__ X, const u16* __restrict__ WgT,
    const u16* __restrict__ WcT, const float* __restrict__ bg,
    const float* __restrict__ bc, float* __restrict__ hF,
    u16* __restrict__ hB, u16* __restrict__ rhB,
    const int* __restrict__ lens, int* bar) {
  __shared__ __align__(16) u16 Wl[48 * K_DIM];  // 147456 B
  const int tid = threadIdx.x;
  const int wgid = blockIdx.x;
  const int ct = wgid >> 2;
  const int mq = wgid & 3;

  // Stage weights once: 48 cols x 1536 k.
  // lc<16: Wg r-col ct*16+lc; lc in [16,32): Wg z-col 1024+ct*16+(lc-16);
  // lc>=32: Wc col ct*16+(lc-32).
#pragma unroll 4
  for (int it = 0; it < 36; ++it) {
    int ci = it * 256 + tid;
    int lc = ci / 192;
    int k0 = (ci - lc * 192) * 8;
    const u16* src = (lc < 16)
        ? WgT + (size_t)(ct * 16 + lc) * K_DIM + k0
        : (lc < 32)
          ? WgT + (size_t)(1024 + ct * 16 + (lc - 16)) * K_DIM + k0
          : WcT + (size_t)(ct * 16 + (lc - 32)) * K_DIM + k0;
    uint4 v = *(const uint4*)src;
    int ofs = lc * 3072 + k0 * 2;
    ofs ^= ((lc & 7) << 4);
    *(uint4*)((char*)Wl + ofs) = v;
  }
  __syncthreads();

  const int lane = tid & 63, wv = tid >> 6;
  const int l15 = lane & 15;
  const int kq8 = (lane >> 4) * 8;
  const int lq4 = (lane >> 4) * 4;
  const int rbase = mq * 64 + wv * 16;
  const u16* Hp = hB + (size_t)(rbase + l15) * U_DIM + kq8;
  const u16* Rp = rhB + (size_t)(rbase + l15) * U_DIM + kq8;
  int* fbase = bar + mq * 2048;

  // Hoisted per-thread constants.
  int len4[4];
#pragma unroll
  for (int q = 0; q < 4; ++q) len4[q] = lens[rbase + lq4 + q];
  const int nc = ct * 16 + l15;                 // this thread's cand/r column
  const float bg0 = bg[nc];                     // r-gate bias
  const float bg1 = bg[1024 + nc];              // z-gate bias
  const float bc0 = bc[nc];

  // Register-resident GRU state for (rows rbase+lq4+q, col nc).
  float h_reg[4] = {0.f, 0.f, 0.f, 0.f};
  float z_reg[4];

  bf16x8 af[16], ah[32];
  int phase = 0;
  for (int t = 0; t < T_DIM; ++t) {
    // ---- Phase A: r/z gates for own 16+16 cols; rh -> rhB (only A-store) --
#pragma unroll
    for (int kb = 0; kb < 32; ++kb) ah[kb] = ld_bf8_coh(Hp + kb * 32);
    const u16* Xt = X + ((size_t)t * B_DIM + rbase + l15) * E_DIM + kq8;
#pragma unroll
    for (int kb = 0; kb < 16; ++kb) af[kb] = *(const bf16x8*)(Xt + kb * 32);

    f32x4 a0 = {0.f, 0.f, 0.f, 0.f}, a1 = {0.f, 0.f, 0.f, 0.f};
#pragma unroll
    for (int kb = 0; kb < 48; ++kb) {
      bf16x8 av = (kb < 16) ? af[kb] : ah[kb - 16];
      bf16x8 b0 = ldsW(Wl, l15, kb * 32 + kq8);       // r cols
      bf16x8 b1 = ldsW(Wl, 16 + l15, kb * 32 + kq8);  // z cols
      a0 = __builtin_amdgcn_mfma_f32_16x16x32_bf16(av, b0, a0, 0, 0, 0);
      a1 = __builtin_amdgcn_mfma_f32_16x16x32_bf16(av, b1, a1, 0, 0, 0);
    }
#pragma unroll
    for (int q = 0; q < 4; ++q) {
      int row = rbase + lq4 + q;
      float r = 1.f / (1.f + __expf(-(a0[q] + bg0)));
      z_reg[q] = 1.f / (1.f + __expf(-(a1[q] + bg1)));
      u16 rv = f2bf(r * h_reg[q]);
      // pack 4 cols (l15 base..base+3) into one u64 exchange
      u32 lo = (u32)rv | ((u32)(u16)__shfl_xor((int)rv, 1) << 16);
      u32 hi = (u32)__shfl_xor((int)lo, 2);
      if ((l15 & 3) == 0) {
        u64 pk = (u64)lo | ((u64)hi << 32);
        st_u64_coh((u64*)(rhB + (size_t)row * U_DIM + nc), pk);
      }
    }
    // Phase-B x-part: own regs + LDS only — overlap with barrier arrival.
    f32x4 a2 = {0.f, 0.f, 0.f, 0.f};
#pragma unroll
    for (int kb = 0; kb < 16; ++kb) {
      bf16x8 b2 = ldsW(Wl, 32 + l15, kb * 32 + kq8);
      a2 = __builtin_amdgcn_mfma_f32_16x16x32_bf16(af[kb], b2, a2, 0, 0, 0);
    }
    group_barrier(fbase, ct, ++phase);

    // ---- Phase B: cand for own 16 cols; h update in-register ----
#pragma unroll
    for (int kb = 0; kb < 32; ++kb) ah[kb] = ld_bf8_coh(Rp + kb * 32);
#pragma unroll
    for (int kb = 0; kb < 32; ++kb) {
      bf16x8 b2 = ldsW(Wl, 32 + l15, (kb + 16) * 32 + kq8);
      a2 = __builtin_amdgcn_mfma_f32_16x16x32_bf16(ah[kb], b2, a2, 0, 0, 0);
    }
#pragma unroll
    for (int q = 0; q < 4; ++q) {
      int row = rbase + lq4 + q;
      float c = tanhf(a2[q] + bc0);
      float hn = z_reg[q] * h_reg[q] + (1.f - z_reg[q]) * c;
      float v = (t < len4[q]) ? hn : h_reg[q];
      h_reg[q] = v;
      u16 hv = f2bf(v);
      u32 lo = (u32)hv | ((u32)(u16)__shfl_xor((int)hv, 1) << 16);
      u32 hi = (u32)__shfl_xor((int)lo, 2);
      if ((l15 & 3) == 0) {
        st_u64_coh((u64*)(hB + (size_t)row * U_DIM + nc),
                   (u64)lo | ((u64)hi << 32));
      }
      if (t == T_DIM - 1) {
        // fp32 h for the MLP head; plain store — kernel boundary publishes it.
        hF[(size_t)row * U_DIM + nc] = v;
      }
    }
    group_barrier(fbase, ct, ++phase);
  }
}

__global__ __launch_bounds__(256) void mlp1_kernel(const float* __restrict__ h,
                                                   const float* __restrict__ W1,
                                                   const float* __restrict__ b1,
                                                   float* __restrict__ o1) {
  int m = blockIdx.x, tid = threadIdx.x;
  __shared__ float xs[1024];
  for (int k = tid; k < 1024; k += 256) xs[k] = h[(size_t)m * 1024 + k];
  __syncthreads();
  for (int n = tid; n < 512; n += 256) {
    float s = b1[n];
    for (int k = 0; k < 1024; ++k) s += xs[k] * W1[(size_t)k * 512 + n];
    o1[(size_t)m * 512 + n] = fmaxf(s, 0.f);
  }
}

__global__ __launch_bounds__(256) void mlp2_kernel(const float* __restrict__ x,
                                                   const float* __restrict__ W2,
                                                   const float* __restrict__ b2,
                                                   float* __restrict__ o2) {
  int m = blockIdx.x, tid = threadIdx.x;
  __shared__ float xs[512];
  for (int k = tid; k < 512; k += 256) xs[k] = x[(size_t)m * 512 + k];
  __syncthreads();
  int n = tid;
  float s = b2[n];
  for (int k = 0; k < 512; ++k) s += xs[k] * W2[(size_t)k * 256 + n];
  o2[(size_t)m * 256 + n] = fmaxf(s, 0.f);
}

__global__ __launch_bounds__(256) void mlp3_kernel(const float* __restrict__ x,
                                                   const float* __restrict__ W3,
                                                   const float* __restrict__ b3,
                                                   float* __restrict__ out) {
  int m = blockIdx.x, tid = threadIdx.x;
  float xk = x[(size_t)m * 256 + tid];
  float p0 = xk * W3[tid * 2 + 0];
  float p1 = xk * W3[tid * 2 + 1];
#pragma unroll
  for (int off = 32; off; off >>= 1) {
    p0 += __shfl_down(p0, off);
    p1 += __shfl_down(p1, off);
  }
  __shared__ float s0[4], s1[4];
  int wave = tid >> 6, lane = tid & 63;
  if (lane == 0) { s0[wave] = p0; s1[wave] = p1; }
  __syncthreads();
  if (tid == 0) {
    float l0 = s0[0] + s0[1] + s0[2] + s0[3] + b3[0];
    float l1 = s1[0] + s1[1] + s1[2] + s1[3] + b3[1];
    out[m * 2 + 0] = l0;
    out[m * 2 + 1] = l1;
    float mx = fmaxf(l0, l1);
    float e0 = __expf(l0 - mx), e1 = __expf(l1 - mx);
    float inv = 1.f / (e0 + e1);
    out[512 + m * 2 + 0] = e0 * inv;
    out[512 + m * 2 + 1] = e1 * inv;
  }
}

extern "C" void kernel_launch(void* const* d_in, const int* in_sizes, int n_in,
                              void* d_out, int out_size, void* d_ws, size_t ws_size,
                              hipStream_t stream) {
  (void)in_sizes; (void)n_in; (void)out_size; (void)ws_size;
  const int* inputs = (const int*)d_in[0];
  const int* lens = (const int*)d_in[1];
  const float* embedder = (const float*)d_in[2];
  const float* Wg = (const float*)d_in[3];
  const float* bg = (const float*)d_in[4];
  const float* Wc = (const float*)d_in[5];
  const float* bc = (const float*)d_in[6];
  const float* W1 = (const float*)d_in[7];
  const float* b1 = (const float*)d_in[8];
  const float* W2 = (const float*)d_in[9];
  const float* b2 = (const float*)d_in[10];
  const float* W3 = (const float*)d_in[11];
  const float* b3 = (const float*)d_in[12];
  float* out = (float*)d_out;

  char* ws = (char*)d_ws;
  size_t off = 0;
  u16* X = (u16*)(ws + off);       off += (size_t)T_DIM * B_DIM * E_DIM * 2;
  u16* WgT = (u16*)(ws + off);     off += (size_t)NG * K_DIM * 2;
  u16* WcT = (u16*)(ws + off);     off += (size_t)U_DIM * K_DIM * 2;
  float* hF = (float*)(ws + off);  off += (size_t)B_DIM * U_DIM * 4;
  u16* hB = (u16*)(ws + off);      off += (size_t)B_DIM * U_DIM * 2;
  u16* rhB = (u16*)(ws + off);     off += (size_t)B_DIM * U_DIM * 2;
  float* o1 = (float*)(ws + off);  off += (size_t)B_DIM * 512 * 4;
  float* o2 = (float*)(ws + off);  off += (size_t)B_DIM * 256 * 4;
  int* bar = (int*)(ws + off);     off += 65536;

  init_kernel<<<dim3(1024), dim3(256), 0, stream>>>(hF, hB, bar);
  wconv_kernel<<<dim3(24, 512), dim3(256), 0, stream>>>(Wg, WgT, NG);
  wconv_kernel<<<dim3(24, 256), dim3(256), 0, stream>>>(Wc, WcT, U_DIM);
  embed_kernel<<<dim3(T_DIM * B_DIM), dim3(128), 0, stream>>>(inputs, embedder, X);

  gru_loop<<<dim3(NWG), dim3(256), 0, stream>>>(X, WgT, WcT, bg, bc, hF, hB, rhB,
                                                lens, bar);

  mlp1_kernel<<<dim3(256), dim3(256), 0, stream>>>(hF, W1, b1, o1);
  mlp2_kernel<<<dim3(256), dim3(256), 0, stream>>>(o1, W2, b2, o2);
  mlp3_kernel<<<dim3(256), dim3(256), 0, stream>>>(o2, W3, b3, out);
}